// Round 1
// baseline (12579.131 us; speedup 1.0000x reference)
//
#include <hip/hip_runtime.h>
#include <hip/hip_bf16.h>

// LSTM encoder: B=64, T=2048, D=256, H=512.
// Persistent-RNN design: 128 wgs (1/CU via 154KB LDS), each owns a
// [768 x 64] bf16 slice of [U;W] resident in LDS. Per timestep:
//   z = [h_{t-1} (bf16) | x_t (fp32->bf16)]  staged in LDS (16 x 768)
//   gates(16x64) = z @ UWslice + b   via mfma_f32_16x16x32_bf16 (K-loop of 24)
//   pointwise i,f,g,o -> c,h ; h published to global (agent-scope atomics)
//   per-batch-tile counting barrier (32 wgs/group) before next step.
// 4 batch-tiles x 32 h-slices; h double-buffered by step parity.

#define B_   64
#define T_   2048
#define D_   256
#define H_   512
#define G4   2048          // 4H
#define KTOT 768           // H + D
#define KK   24            // KTOT / 32
#define TILES 4            // B/16
#define SLICES 32          // H/16
#define GRP  32            // wgs per barrier group
#define ZS   776           // z row stride (bf16 elems), 768 + 8 pad
#define UWP  40            // UWL row length (bf16 elems), 32 + 8 pad

#define OFF_UWL 0
#define SZ_UWL  (KK * 64 * UWP * 2)          // 122880
#define OFF_Z   (OFF_UWL + SZ_UWL)           // 122880
#define SZ_Z    (16 * ZS * 2)                // 24832
#define OFF_GT  (OFF_Z + SZ_Z)               // 147712
#define SZ_GT   (4 * 16 * 17 * 4)            // 4352
#define OFF_CS  (OFF_GT + SZ_GT)             // 152064
#define SZ_CS   (16 * 17 * 4)                // 1088
#define OFF_HS  (OFF_CS + SZ_CS)             // 153152
#define SZ_HS   (16 * 16 * 2)                // 512
#define OFF_BS  (OFF_HS + SZ_HS)             // 153664
#define SZ_BS   (64 * 4)                     // 256
#define SMEM_BYTES (OFF_BS + SZ_BS)          // 153920 < 160 KiB

typedef __attribute__((ext_vector_type(8))) short v8s;
typedef __attribute__((ext_vector_type(4))) float v4f;

__device__ __forceinline__ unsigned short f2bf(float f) {
    unsigned u = __builtin_bit_cast(unsigned, f);
    u = (u + 0x7FFFu + ((u >> 16) & 1u)) >> 16;   // RTNE
    return (unsigned short)u;
}

__device__ __forceinline__ float fast_sigmoid(float v) {
    return 1.0f / (1.0f + __expf(-v));
}
__device__ __forceinline__ float fast_tanh(float v) {
    float x = fminf(fmaxf(v, -15.0f), 15.0f);
    float e = __expf(2.0f * x);
    return (e - 1.0f) / (e + 1.0f);
}

__global__ void __launch_bounds__(256, 1)
lstm_persist(const float* __restrict__ x, const float* __restrict__ W,
             const float* __restrict__ U, const float* __restrict__ bias,
             float* __restrict__ out, unsigned* __restrict__ cnt,
             unsigned* __restrict__ hbuf /* u32 view of bf16[2][64][512] */)
{
    extern __shared__ char smem[];
    unsigned short* UWL = (unsigned short*)(smem + OFF_UWL); // [KK][64][UWP]
    unsigned short* z   = (unsigned short*)(smem + OFF_Z);   // [16][ZS]
    float*          gt  = (float*)(smem + OFF_GT);           // [4][16][17]
    float*          cs  = (float*)(smem + OFF_CS);           // [16][17]
    unsigned short* hs  = (unsigned short*)(smem + OFF_HS);  // [16][16]
    float*          bs  = (float*)(smem + OFF_BS);           // [64]

    const int tid  = threadIdx.x;
    const int g    = blockIdx.x;
    const int tile = g & (TILES - 1);   // batch tile 0..3 (16 batches)
    const int s    = g >> 2;            // h-slice 0..31 (16 h-cols)
    const int l    = tid & 63;
    const int w    = tid >> 6;          // wave 0..3 == gate index

    // ---- one-time: stage [U;W] slice (bf16) + bias into LDS ----
    for (int idx = tid; idx < KTOT * 64; idx += 256) {
        int k = idx >> 6;          // 0..767
        int n = idx & 63;          // local gate col
        int gcol = (n >> 4) * H_ + s * 16 + (n & 15);
        float v = (k < H_) ? U[(size_t)k * G4 + gcol]
                           : W[(size_t)(k - H_) * G4 + gcol];
        UWL[((k >> 5) * 64 + n) * UWP + (k & 31)] = f2bf(v);
    }
    if (tid < 64) {
        int gcol = (tid >> 4) * H_ + s * 16 + (tid & 15);
        bs[tid] = bias[gcol];
    }
    {   // zero cell state + zero h-part of z for t=0
        int b = tid >> 4, jj = tid & 15;
        cs[b * 17 + jj] = 0.0f;
        unsigned long long* dst = (unsigned long long*)(z + b * ZS + jj * 32);
        #pragma unroll
        for (int q = 0; q < 8; ++q) dst[q] = 0ull;
    }
    {   // stage x(t=0) -> z x-region
        int r = tid >> 4, u = tid & 15;
        const float4* xs = (const float4*)(x + ((size_t)(tile * 16 + r) * T_ + 0) * D_ + u * 16);
        unsigned* dst = (unsigned*)(z + r * ZS + H_ + u * 16);
        #pragma unroll
        for (int q = 0; q < 4; ++q) {
            float4 v = xs[q];
            dst[q * 2 + 0] = (unsigned)f2bf(v.x) | ((unsigned)f2bf(v.y) << 16);
            dst[q * 2 + 1] = (unsigned)f2bf(v.z) | ((unsigned)f2bf(v.w) << 16);
        }
    }

    const unsigned short* arow = z   + (l & 15) * ZS + (l >> 4) * 8;
    const unsigned short* brow = UWL + (w * 16 + (l & 15)) * UWP + (l >> 4) * 8;
    const float bv = bs[0];  // placeholder; real read after sync below
    (void)bv;

    unsigned target = 0;

    for (int t = 0; t < T_; ++t) {
        if (t > 0) {
            // stage h_{t-1} from global (agent-scope, L2-coherent) into z
            int r = tid >> 4, u = tid & 15;
            const unsigned long long* src = (const unsigned long long*)
                (hbuf + (size_t)(t & 1) * (B_ * H_ / 2)
                      + ((tile * 16 + r) * H_ + u * 32) / 2);
            unsigned long long* dst = (unsigned long long*)(z + r * ZS + u * 32);
            #pragma unroll
            for (int q = 0; q < 8; ++q)
                dst[q] = __hip_atomic_load(src + q, __ATOMIC_RELAXED,
                                           __HIP_MEMORY_SCOPE_AGENT);
        }
        __syncthreads();   // z (h + x) ready; UWL/bias ready on first iter

        // ---- gates(16x64) = z @ UWslice + b ; wave w owns gate w (16 cols) ----
        float bcol = bs[w * 16 + (l & 15)];
        v4f acc = {bcol, bcol, bcol, bcol};
        #pragma unroll
        for (int kk = 0; kk < KK; ++kk) {
            v8s a  = *(const v8s*)(arow + kk * 32);
            v8s bf = *(const v8s*)(brow + kk * (64 * UWP));
            acc = __builtin_amdgcn_mfma_f32_16x16x32_bf16(a, bf, acc, 0, 0, 0);
        }
        {   // activation; D layout: row = (l>>4)*4 + rr (batch), col = l&15 (jj)
            int col = l & 15, quad = l >> 4;
            #pragma unroll
            for (int rr = 0; rr < 4; ++rr) {
                float v = acc[rr];
                float a = (w == 2) ? fast_tanh(v) : fast_sigmoid(v);
                gt[(w * 16 + (quad * 4 + rr)) * 17 + col] = a;
            }
        }
        __syncthreads();   // gt ready; z fully consumed by MFMA

        // ---- pointwise c,h update (thread = (batch b, col jj)) ----
        {
            int b = tid >> 4, jj = tid & 15;
            float iv = gt[(0 * 16 + b) * 17 + jj];
            float fv = gt[(1 * 16 + b) * 17 + jj];
            float gv = gt[(2 * 16 + b) * 17 + jj];
            float ov = gt[(3 * 16 + b) * 17 + jj];
            float c  = cs[b * 17 + jj];
            float cn = fv * c + iv * gv;
            cs[b * 17 + jj] = cn;
            float h = ov * fast_tanh(cn);
            if (t == T_ - 1) {
                out[(size_t)(tile * 16 + b) * H_ + s * 16 + jj] = h;
                out[(size_t)B_ * H_ + (size_t)(tile * 16 + b) * H_ + s * 16 + jj] = cn;
            } else {
                hs[b * 16 + jj] = f2bf(h);
            }
        }
        if (t < T_ - 1) {
            // prefetch x(t+1) into z x-region (safe: MFMA reads done at gt-sync)
            int r = tid >> 4, u = tid & 15;
            const float4* xs = (const float4*)
                (x + ((size_t)(tile * 16 + r) * T_ + (t + 1)) * D_ + u * 16);
            unsigned* dst = (unsigned*)(z + r * ZS + H_ + u * 16);
            #pragma unroll
            for (int q = 0; q < 4; ++q) {
                float4 v = xs[q];
                dst[q * 2 + 0] = (unsigned)f2bf(v.x) | ((unsigned)f2bf(v.y) << 16);
                dst[q * 2 + 1] = (unsigned)f2bf(v.z) | ((unsigned)f2bf(v.w) << 16);
            }
        }
        __syncthreads();   // hs ready for publish; x writes ordered for next step

        if (t < T_ - 1) {
            // publish h slice: 16 rows x 16 bf16 = 128 u32
            if (tid < 128) {
                int b = tid >> 3, q = tid & 7;
                unsigned val = ((unsigned*)hs)[b * 8 + q];
                unsigned* dst = hbuf + (size_t)((t + 1) & 1) * (B_ * H_ / 2)
                                     + ((tile * 16 + b) * H_ + s * 16) / 2 + q;
                __hip_atomic_store(dst, val, __ATOMIC_RELAXED,
                                   __HIP_MEMORY_SCOPE_AGENT);
            }
            target += GRP;
            if (tid == 0) {
                __hip_atomic_fetch_add(&cnt[tile * 64], 1u, __ATOMIC_ACQ_REL,
                                       __HIP_MEMORY_SCOPE_AGENT);
                while (__hip_atomic_load(&cnt[tile * 64], __ATOMIC_ACQUIRE,
                                         __HIP_MEMORY_SCOPE_AGENT) < target) { }
            }
            __syncthreads();   // broadcast barrier completion to all waves
        }
    }
}

extern "C" void kernel_launch(void* const* d_in, const int* in_sizes, int n_in,
                              void* d_out, int out_size, void* d_ws, size_t ws_size,
                              hipStream_t stream) {
    const float* x  = (const float*)d_in[0];   // [64,2048,256]
    const float* W  = (const float*)d_in[1];   // [256,2048]
    const float* U  = (const float*)d_in[2];   // [512,2048]
    const float* bb = (const float*)d_in[3];   // [2048]
    float* out = (float*)d_out;                // [2][64][512] fp32 (h, c)

    unsigned* cnt  = (unsigned*)d_ws;                       // 4 counters, 256B apart
    unsigned* hbuf = (unsigned*)((char*)d_ws + 4096);       // bf16[2][64][512]

    // zero barrier counters (+ h buffer, harmless) — ws is poisoned each call
    hipMemsetAsync(d_ws, 0, 4096 + (size_t)2 * B_ * H_ * 2, stream);

    hipFuncSetAttribute((const void*)lstm_persist,
                        hipFuncAttributeMaxDynamicSharedMemorySize, SMEM_BYTES);

    lstm_persist<<<TILES * SLICES, 256, SMEM_BYTES, stream>>>(
        x, W, U, bb, out, cnt, hbuf);
}

// Round 2
// 9250.818 us; speedup vs baseline: 1.3598x; 1.3598x over previous
//
#include <hip/hip_runtime.h>
#include <hip/hip_bf16.h>

// LSTM encoder: B=64, T=2048, D=256, H=512.
// Persistent-RNN: 128 wgs (1/CU via ~149KB LDS), each owns a [768 x 64] bf16
// slice of [U;W] in LDS. Per timestep:
//   z = [h_{t-1} | x_t]  (16 x 768 bf16 in LDS, contiguous staging)
//   gates(16x64) = z @ UWslice + b  (mfma_f32_16x16x32_bf16, 4 indep accs)
//   pointwise -> c (register), h published direct from regs (shfl-paired u32)
//   counter barrier per batch-tile group (32 wgs), ALL-RELAXED agent atomics
//   (no acquire/release -> no per-step L2 invalidate/writeback).
// Ordering: publish stores are sc1 (coherence-point write-through); each wave
// drains vmcnt before the (D) barrier; only then tid0 increments the counter.
// Consumers' relaxed sc1 loads read the coherence point -> no stale data.

#define B_   64
#define T_   2048
#define D_   256
#define H_   512
#define G4   2048          // 4H
#define KTOT 768           // H + D
#define KK   24            // KTOT / 32
#define TILES 4            // B/16
#define SLICES 32          // H/16
#define GRP  32            // wgs per barrier group
#define ZS   776           // z row stride (bf16 elems), 768 + 8 pad
#define UWP  40            // UWL row length (bf16 elems), 32 + 8 pad

#define OFF_UWL 0
#define SZ_UWL  (KK * 64 * UWP * 2)          // 122880
#define OFF_Z   (OFF_UWL + SZ_UWL)           // 122880
#define SZ_Z    (16 * ZS * 2)                // 24832
#define OFF_GT  (OFF_Z + SZ_Z)               // 147712
#define SZ_GT   (4 * 16 * 17 * 4)            // 4352
#define OFF_BS  (OFF_GT + SZ_GT)             // 152064
#define SZ_BS   (64 * 4)                     // 256
#define SMEM_BYTES (OFF_BS + SZ_BS)          // 152320 < 160 KiB

typedef __attribute__((ext_vector_type(8))) short v8s;
typedef __attribute__((ext_vector_type(4))) float v4f;

__device__ __forceinline__ unsigned short f2bf(float f) {
    unsigned u = __builtin_bit_cast(unsigned, f);
    u = (u + 0x7FFFu + ((u >> 16) & 1u)) >> 16;   // RTNE
    return (unsigned short)u;
}
__device__ __forceinline__ float fast_sigmoid(float v) {
    return 1.0f / (1.0f + __expf(-v));
}
__device__ __forceinline__ float fast_tanh(float v) {
    float x = fminf(fmaxf(v, -15.0f), 15.0f);
    float e = __expf(2.0f * x);
    return (e - 1.0f) / (e + 1.0f);
}

__global__ void __launch_bounds__(256, 1)
lstm_persist(const float* __restrict__ x, const float* __restrict__ W,
             const float* __restrict__ U, const float* __restrict__ bias,
             float* __restrict__ out, unsigned* __restrict__ cnt,
             unsigned* __restrict__ hbuf /* u32 view of bf16[2][64][512] */)
{
    extern __shared__ char smem[];
    unsigned short* UWL = (unsigned short*)(smem + OFF_UWL); // [KK][64][UWP]
    unsigned short* z   = (unsigned short*)(smem + OFF_Z);   // [16][ZS]
    float*          gt  = (float*)(smem + OFF_GT);           // [4][16][17]
    float*          bs  = (float*)(smem + OFF_BS);           // [64]

    const int tid  = threadIdx.x;
    const int g    = blockIdx.x;
    const int tile = g & (TILES - 1);   // batch tile 0..3 (16 batches)
    const int s    = g >> 2;            // h-slice 0..31 (16 h-cols)
    const int l    = tid & 63;
    const int w    = tid >> 6;          // wave 0..3 == gate index
    const int b    = tid >> 4;          // pointwise: batch row 0..15
    const int jj   = tid & 15;          // pointwise: h col 0..15

    // ---- one-time: stage [U;W] slice (bf16) + bias into LDS ----
    for (int idx = tid; idx < KTOT * 64; idx += 256) {
        int k = idx >> 6;          // 0..767
        int n = idx & 63;          // local gate col
        int gcol = (n >> 4) * H_ + s * 16 + (n & 15);
        float v = (k < H_) ? U[(size_t)k * G4 + gcol]
                           : W[(size_t)(k - H_) * G4 + gcol];
        UWL[((k >> 5) * 64 + n) * UWP + (k & 31)] = f2bf(v);
    }
    if (tid < 64) {
        int gcol = (tid >> 4) * H_ + s * 16 + (tid & 15);
        bs[tid] = bias[gcol];
    }
    // zero h-region of z for t=0 (contiguous, conflict-free)
    #pragma unroll
    for (int p = 0; p < 8; ++p) {
        int n = p * 256 + tid;          // 0..2047 over 16 rows x 128 u64
        int row = n >> 7, col = n & 127;
        *(unsigned long long*)(z + row * ZS + col * 4) = 0ull;
    }
    // stage x(t=0) -> z x-region (contiguous lanes -> conflict-free)
    #pragma unroll
    for (int p = 0; p < 4; ++p) {
        int n = p * 256 + tid;          // 0..1023 over 16 rows x 64 float4
        int row = n >> 6, c4 = n & 63;
        float4 v = *(const float4*)(x + ((size_t)(tile * 16 + row) * T_ + 0) * D_ + c4 * 4);
        unsigned long long pk =
            (unsigned long long)((unsigned)f2bf(v.x) | ((unsigned)f2bf(v.y) << 16)) |
            ((unsigned long long)((unsigned)f2bf(v.z) | ((unsigned)f2bf(v.w) << 16)) << 32);
        *(unsigned long long*)(z + row * ZS + H_ + c4 * 4) = pk;
    }

    const unsigned short* arow = z   + (l & 15) * ZS + (l >> 4) * 8;
    const unsigned short* brow = UWL + (w * 16 + (l & 15)) * UWP + (l >> 4) * 8;
    unsigned* myCnt = &cnt[tile * 64];

    float creg = 0.0f;       // cell state for (b, jj) — thread-private
    unsigned target = 0;

    for (int t = 0; t < T_; ++t) {
        if (t > 0) {
            // stage h_{t-1}: contiguous u64 relaxed sc1 loads -> contiguous LDS
            const unsigned long long* hb64 = (const unsigned long long*)hbuf;
            size_t base = (size_t)(t & 1) * 8192;   // 64*512*2B / 8
            #pragma unroll
            for (int p = 0; p < 8; ++p) {
                int n = p * 256 + tid;
                int row = n >> 7, col = n & 127;
                unsigned long long v = __hip_atomic_load(
                    hb64 + base + (size_t)(tile * 16 + row) * 128 + col,
                    __ATOMIC_RELAXED, __HIP_MEMORY_SCOPE_AGENT);
                *(unsigned long long*)(z + row * ZS + col * 4) = v;
            }
        }
        __syncthreads();   // (A) z ready

        // ---- gates(16x64) = z @ UWslice + b ; wave w owns gate w ----
        v4f acc0 = {0,0,0,0}, acc1 = {0,0,0,0}, acc2 = {0,0,0,0}, acc3 = {0,0,0,0};
        #pragma unroll
        for (int kk = 0; kk < KK; kk += 4) {
            v8s a0 = *(const v8s*)(arow + (kk + 0) * 32);
            v8s b0 = *(const v8s*)(brow + (kk + 0) * (64 * UWP));
            acc0 = __builtin_amdgcn_mfma_f32_16x16x32_bf16(a0, b0, acc0, 0, 0, 0);
            v8s a1 = *(const v8s*)(arow + (kk + 1) * 32);
            v8s b1 = *(const v8s*)(brow + (kk + 1) * (64 * UWP));
            acc1 = __builtin_amdgcn_mfma_f32_16x16x32_bf16(a1, b1, acc1, 0, 0, 0);
            v8s a2 = *(const v8s*)(arow + (kk + 2) * 32);
            v8s b2 = *(const v8s*)(brow + (kk + 2) * (64 * UWP));
            acc2 = __builtin_amdgcn_mfma_f32_16x16x32_bf16(a2, b2, acc2, 0, 0, 0);
            v8s a3 = *(const v8s*)(arow + (kk + 3) * 32);
            v8s b3 = *(const v8s*)(brow + (kk + 3) * (64 * UWP));
            acc3 = __builtin_amdgcn_mfma_f32_16x16x32_bf16(a3, b3, acc3, 0, 0, 0);
        }
        {
            v4f acc = (acc0 + acc1) + (acc2 + acc3);
            float bcol = bs[w * 16 + (l & 15)];
            int col = l & 15, quad = l >> 4;
            #pragma unroll
            for (int rr = 0; rr < 4; ++rr) {
                float v = acc[rr] + bcol;
                float a = (w == 2) ? fast_tanh(v) : fast_sigmoid(v);
                gt[(w * 16 + (quad * 4 + rr)) * 17 + col] = a;
            }
        }
        __syncthreads();   // (B) gt ready; z fully consumed

        // ---- pointwise c,h for (b, jj); c in register ----
        float iv = gt[(0 * 16 + b) * 17 + jj];
        float fv = gt[(1 * 16 + b) * 17 + jj];
        float gv = gt[(2 * 16 + b) * 17 + jj];
        float ov = gt[(3 * 16 + b) * 17 + jj];
        float cn = fv * creg + iv * gv;
        creg = cn;
        float h = ov * fast_tanh(cn);

        if (t == T_ - 1) {
            out[(size_t)(tile * 16 + b) * H_ + s * 16 + jj] = h;
            out[(size_t)B_ * H_ + (size_t)(tile * 16 + b) * H_ + s * 16 + jj] = cn;
        } else {
            // publish h direct from regs: pair adjacent jj via shfl -> u32 store
            unsigned hu = (unsigned)f2bf(h);
            unsigned nb = (unsigned)__shfl_xor((int)hu, 1, 64);
            if ((jj & 1) == 0) {
                unsigned val = hu | (nb << 16);
                size_t idx = (size_t)((t + 1) & 1) * 16384
                           + ((size_t)(tile * 16 + b) * H_ + s * 16 + jj) / 2;
                __hip_atomic_store(hbuf + idx, val, __ATOMIC_RELAXED,
                                   __HIP_MEMORY_SCOPE_AGENT);
            }
            asm volatile("s_waitcnt vmcnt(0)" ::: "memory");  // drain own stores
            __syncthreads();   // (D) all waves' publishes drained

            target += GRP;
            if (tid == 0) {
                __hip_atomic_fetch_add(myCnt, 1u, __ATOMIC_RELAXED,
                                       __HIP_MEMORY_SCOPE_AGENT);
            }
            // overlap barrier propagation with x(t+1) prefetch
            #pragma unroll
            for (int p = 0; p < 4; ++p) {
                int n = p * 256 + tid;
                int row = n >> 6, c4 = n & 63;
                float4 v = *(const float4*)
                    (x + ((size_t)(tile * 16 + row) * T_ + (t + 1)) * D_ + c4 * 4);
                unsigned long long pk =
                    (unsigned long long)((unsigned)f2bf(v.x) | ((unsigned)f2bf(v.y) << 16)) |
                    ((unsigned long long)((unsigned)f2bf(v.z) | ((unsigned)f2bf(v.w) << 16)) << 32);
                *(unsigned long long*)(z + row * ZS + H_ + c4 * 4) = pk;
            }
            if (tid == 0) {
                while (__hip_atomic_load(myCnt, __ATOMIC_RELAXED,
                                         __HIP_MEMORY_SCOPE_AGENT) < target) {
                    __builtin_amdgcn_s_sleep(1);
                }
            }
            __syncthreads();   // (E) barrier done; proceed to next step
        }
    }
}

extern "C" void kernel_launch(void* const* d_in, const int* in_sizes, int n_in,
                              void* d_out, int out_size, void* d_ws, size_t ws_size,
                              hipStream_t stream) {
    const float* x  = (const float*)d_in[0];   // [64,2048,256]
    const float* W  = (const float*)d_in[1];   // [256,2048]
    const float* U  = (const float*)d_in[2];   // [512,2048]
    const float* bb = (const float*)d_in[3];   // [2048]
    float* out = (float*)d_out;                // [2][64][512] fp32 (h, c)

    unsigned* cnt  = (unsigned*)d_ws;                       // 4 counters, 256B apart
    unsigned* hbuf = (unsigned*)((char*)d_ws + 4096);       // bf16[2][64][512]

    // zero barrier counters (ws is re-poisoned 0xAA before every call)
    hipMemsetAsync(d_ws, 0, 4096 + (size_t)2 * B_ * H_ * 2, stream);

    hipFuncSetAttribute((const void*)lstm_persist,
                        hipFuncAttributeMaxDynamicSharedMemorySize, SMEM_BYTES);

    lstm_persist<<<TILES * SLICES, 256, SMEM_BYTES, stream>>>(
        x, W, U, bb, out, cnt, hbuf);
}